// Round 6
// baseline (150.087 us; speedup 1.0000x reference)
//
#include <hip/hip_runtime.h>
#include <math.h>

// Problem dims (fixed by setup_inputs): n=32, t=8, c=128, h=w=32
#define TC  1024   // t*c channels
#define P_  1024   // h*w pixels
#define KC  64     // int(c*0.5)
#define KT  4      // int(t*0.5)

typedef float vfloat4 __attribute__((ext_vector_type(4)));   // native vec for NT store

// workspace layout (float offsets):
//   avg    [0,      32768)    per (n,t,c) spatial mean
//   mx     [32768,  65536)    per (n,t,c) spatial max
//   mask_c [65536,  66560)    int, batch-union channel-topk mask
//   mask_t [66560,  67584)    int, batch-union time-topk mask
//   cnt    [67584,  67616)    int, per-n K4 completion counters (32)
//   flag   [67616,  68640)    float XOR mask (im=1)
//   im_map [68640,  101408)   [n][pix]
//   sub_map[101408, 134176)   [n][pix]
//   part   [134176, 658464)   [cq=4][n=32][stat=4][pix=1024] pooled partials

// ---------- K1: spatial mean/max, one wave per (n,t,c) row -------------------
// 8192 blocks x 256 thr = 4 waves; wave w handles row blockIdx*4+w.
// Lane l reads float4s l, l+64, l+128, l+192 (coalesced, ILP 4), then a pure
// 6-step shfl reduce. Block 0 also zeros masks+cnt (2080 ints, stream-ordered
// before K2/K4 consume them).
__global__ __launch_bounds__(256) void k1_reduce(const float* __restrict__ x,
                                                 float* __restrict__ avg,
                                                 float* __restrict__ mx,
                                                 int* __restrict__ zero_region) {
    if (blockIdx.x == 0) {
        for (int j = threadIdx.x; j < 2080; j += 256) zero_region[j] = 0;
    }
    int wid = threadIdx.x >> 6, lane = threadIdx.x & 63;
    int r = blockIdx.x * 4 + wid;             // r = n*1024 + t*128 + c
    const float4* xp = (const float4*)(x + (size_t)r * P_) + lane;
    float4 a = xp[0], b = xp[64], c = xp[128], d = xp[192];
    float s = ((a.x + a.y) + (a.z + a.w)) + ((b.x + b.y) + (b.z + b.w))
            + ((c.x + c.y) + (c.z + c.w)) + ((d.x + d.y) + (d.z + d.w));
    float m = fmaxf(fmaxf(fmaxf(fmaxf(a.x, a.y), fmaxf(a.z, a.w)),
                          fmaxf(fmaxf(b.x, b.y), fmaxf(b.z, b.w))),
                    fmaxf(fmaxf(fmaxf(c.x, c.y), fmaxf(c.z, c.w)),
                          fmaxf(fmaxf(d.x, d.y), fmaxf(d.z, d.w))));
    #pragma unroll
    for (int off = 32; off > 0; off >>= 1) {
        s += __shfl_down(s, off);
        m  = fmaxf(m, __shfl_down(m, off));
    }
    if (lane == 0) {
        avg[r] = s * (1.0f / 1024.0f);
        mx[r]  = m;
    }
}

// ---------- K2: map_add + fc + exact top-k rank masks; block = (n, tt) -------
__global__ __launch_bounds__(256) void k2_map(const float* __restrict__ avg,
                                              const float* __restrict__ mx,
                                              const float* __restrict__ alpha,
                                              const float* __restrict__ beta,
                                              const float* __restrict__ wfc,
                                              int* __restrict__ mask_c,
                                              int* __restrict__ mask_t) {
    __shared__ float m[TC], mf[TC], w[64];
    int n = blockIdx.x >> 3, tt = blockIdx.x & 7;
    float a0 = alpha[0], b0 = beta[0];
    if (threadIdx.x < 64) w[threadIdx.x] = wfc[threadIdx.x];
    for (int i = threadIdx.x; i < TC; i += 256) {
        float a = avg[n * TC + i], b = mx[n * TC + i];
        m[i] = 0.5f * (a + b) + a0 * a + b0 * b;
    }
    __syncthreads();
    // fc along time: mf[s*128+c] = sum_t m[t*128+c] * W[s][t]
    for (int i = threadIdx.x; i < TC; i += 256) {
        int s = i >> 7, cc = i & 127;
        float acc = 0.0f;
        #pragma unroll
        for (int t2 = 0; t2 < 8; ++t2) acc += m[t2 * 128 + cc] * w[s * 8 + t2];
        mf[i] = acc;
    }
    __syncthreads();
    // exact lax.top_k emulation for row tt: selected iff
    //   #{j: v_j > v_i} + #{j: v_j == v_i && j < i} < k
    if (threadIdx.x < 128) {
        int cc = threadIdx.x, i = tt * 128 + cc;
        float v = mf[i];
        int rc = 0;
        #pragma unroll 16
        for (int c2 = 0; c2 < 128; ++c2) {
            float u = mf[tt * 128 + c2];
            rc += (u > v) || (u == v && c2 < cc);
        }
        if (rc < KC) mask_c[i] = 1;   // benign race: all writers store 1
        int rt = 0;
        #pragma unroll
        for (int t2 = 0; t2 < 8; ++t2) {
            float u = mf[t2 * 128 + cc];
            rt += (u > v) || (u == v && t2 < tt);
        }
        if (rt < KT) mask_t[i] = 1;
    }
}

// ---------- K4: masked channel stats + (last block per n) combine + conv ------
// 512 blocks x 256 thr; block = (n, pq, cq). Partial phase as before; then
// CUB-style per-n completion: the 16th block for n combines the 4 channel-
// quarter partials and runs the 3x3 conv + sigmoid for that n.
__global__ __launch_bounds__(256) void k4_partial(const float* __restrict__ x,
                                                  const int* __restrict__ mask_c,
                                                  const int* __restrict__ mask_t,
                                                  int* __restrict__ cnt,
                                                  float* __restrict__ flag_out,
                                                  float* __restrict__ part,
                                                  const float* __restrict__ w1,
                                                  const float* __restrict__ w2,
                                                  float* __restrict__ im_map,
                                                  float* __restrict__ sub_map) {
    int b = blockIdx.x;
    int cq = b & 3, pq = (b >> 2) & 3, n = b >> 4;
    __shared__ float sf[256];
    __shared__ float4 red[4][4][64];   // [stat][cg][l]
    __shared__ float sp[4][P_];        // combine/conv staging (last block only)
    __shared__ int is_last;
    {
        int i = threadIdx.x;
        int ch = cq * 256 + i;
        float f = ((mask_c[ch] != 0) != (mask_t[ch] != 0)) ? 1.0f : 0.0f;
        sf[i] = f;
        if (n == 0 && pq == 0) flag_out[ch] = f;
    }
    __syncthreads();
    int l = threadIdx.x & 63, cg = threadIdx.x >> 6;
    int f4p = pq * 64 + l;
    int ch0 = cq * 256 + cg * 64;
    const float4* xb = (const float4*)x + ((size_t)(n * TC + ch0)) * 256 + f4p;
    float4 ims  = {0.f, 0.f, 0.f, 0.f};
    float4 subs = {0.f, 0.f, 0.f, 0.f};
    float4 imm  = {-INFINITY, -INFINITY, -INFINITY, -INFINITY};
    float4 subm = {-INFINITY, -INFINITY, -INFINITY, -INFINITY};
    #pragma unroll 8
    for (int k = 0; k < 64; ++k) {
        float4 v = xb[(size_t)k * 256];
        float f = sf[cg * 64 + k];
        float iv;
        iv = v.x * f; ims.x += iv; imm.x = fmaxf(imm.x, iv);
        v.x -= iv;    subs.x += v.x; subm.x = fmaxf(subm.x, v.x);
        iv = v.y * f; ims.y += iv; imm.y = fmaxf(imm.y, iv);
        v.y -= iv;    subs.y += v.y; subm.y = fmaxf(subm.y, v.y);
        iv = v.z * f; ims.z += iv; imm.z = fmaxf(imm.z, iv);
        v.z -= iv;    subs.z += v.z; subm.z = fmaxf(subm.z, v.z);
        iv = v.w * f; ims.w += iv; imm.w = fmaxf(imm.w, iv);
        v.w -= iv;    subs.w += v.w; subm.w = fmaxf(subm.w, v.w);
    }
    red[0][cg][l] = ims;
    red[1][cg][l] = imm;
    red[2][cg][l] = subs;
    red[3][cg][l] = subm;
    __syncthreads();
    if (threadIdx.x < 64) {
        float4 s0 = red[0][0][l], s1 = red[1][0][l], s2 = red[2][0][l], s3 = red[3][0][l];
        #pragma unroll
        for (int g = 1; g < 4; ++g) {
            float4 a = red[0][g][l], bq = red[1][g][l], c = red[2][g][l], d = red[3][g][l];
            s0.x += a.x; s0.y += a.y; s0.z += a.z; s0.w += a.w;
            s1.x = fmaxf(s1.x, bq.x); s1.y = fmaxf(s1.y, bq.y);
            s1.z = fmaxf(s1.z, bq.z); s1.w = fmaxf(s1.w, bq.w);
            s2.x += c.x; s2.y += c.y; s2.z += c.z; s2.w += c.w;
            s3.x = fmaxf(s3.x, d.x); s3.y = fmaxf(s3.y, d.y);
            s3.z = fmaxf(s3.z, d.z); s3.w = fmaxf(s3.w, d.w);
        }
        float4* pp = (float4*)part + ((size_t)(cq * 32 + n) * 4) * 256 + f4p;
        pp[0]   = s0;
        pp[256] = s1;
        pp[512] = s2;
        pp[768] = s3;
    }
    // ---- completion protocol: release stores, count, last block continues ----
    __threadfence();                       // make this block's part[] visible
    __syncthreads();
    if (threadIdx.x == 0) {
        int old = atomicAdd(&cnt[n], 1);
        is_last = (old == 15);
    }
    __syncthreads();
    if (!is_last) return;
    __threadfence();                       // acquire: see all 16 blocks' part[]
    // combine 4 chan-quarters -> pooled in LDS
    for (int p = threadIdx.x; p < P_; p += 256) {
        float s_im = 0.f, s_sub = 0.f, m_im = -INFINITY, m_sub = -INFINITY;
        #pragma unroll
        for (int q = 0; q < 4; ++q) {
            size_t base = ((size_t)(q * 32 + n) * 4) * P_ + p;
            s_im  += part[base];
            m_im   = fmaxf(m_im, part[base + 1024]);
            s_sub += part[base + 2048];
            m_sub  = fmaxf(m_sub, part[base + 3072]);
        }
        sp[0][p] = s_im  * (2.0f / 1024.0f);   // mean / LAM
        sp[1][p] = m_im;
        sp[2][p] = s_sub * (2.0f / 1024.0f);   // mean / (1-LAM)
        sp[3][p] = m_sub;
    }
    __syncthreads();
    // 3x3 SAME conv (2ch->1) + sigmoid for both maps
    for (int p = threadIdx.x; p < P_; p += 256) {
        int y = p >> 5, xx = p & 31;
        float acc1 = 0.0f, acc2 = 0.0f;
        #pragma unroll
        for (int i = 0; i < 2; ++i)
            #pragma unroll
            for (int dy = 0; dy < 3; ++dy) {
                int yy = y + dy - 1;
                if (yy < 0 || yy >= 32) continue;
                #pragma unroll
                for (int dx = 0; dx < 3; ++dx) {
                    int xc = xx + dx - 1;
                    if (xc < 0 || xc >= 32) continue;
                    acc1 += sp[i][yy * 32 + xc]     * w1[i * 9 + dy * 3 + dx];
                    acc2 += sp[2 + i][yy * 32 + xc] * w2[i * 9 + dy * 3 + dx];
                }
            }
        im_map[n * P_ + p]  = 1.0f / (1.0f + expf(-acc1));
        sub_map[n * P_ + p] = 1.0f / (1.0f + expf(-acc2));
    }
}

// ---------- K6: out = x * (flag ? im_map : sub_map); 4 float4/thr, NT stores --
// g = global thread id; n = g>>16; rem = g&65535 -> ch = rem>>8, pixf4 = rem&255.
// j-step adds 256 channels (65536 float4) within the same n; full coverage of
// [0, 262144) float4 per n, same map pixel for all 4 steps.
__global__ __launch_bounds__(256) void k6_out(const float* __restrict__ x,
                                              const float* __restrict__ flag,
                                              const float* __restrict__ im_map,
                                              const float* __restrict__ sub_map,
                                              float* __restrict__ out) {
    int g   = blockIdx.x * 256 + threadIdx.x;   // 0 .. 2097151
    int n   = g >> 16;
    int rem = g & 65535;
    int ch    = rem >> 8;                       // 0..255 (channel row base)
    int pixf4 = rem & 255;
    size_t base = ((size_t)n << 18) + rem;      // float4 index
    const float4* xp = (const float4*)x + base;
    const float4* imb  = (const float4*)im_map  + n * 256 + pixf4;
    const float4* subb = (const float4*)sub_map + n * 256 + pixf4;
    float4 im_v  = *imb;
    float4 sub_v = *subb;
    #pragma unroll
    for (int j = 0; j < 4; ++j) {
        float4 xv = xp[j * 65536];              // +256 channels, same pixel
        bool im = flag[ch + j * 256] != 0.0f;
        float4 mv = im ? im_v : sub_v;
        vfloat4 o;
        o.x = xv.x * mv.x; o.y = xv.y * mv.y; o.z = xv.z * mv.z; o.w = xv.w * mv.w;
        __builtin_nontemporal_store(o, (vfloat4*)out + base + (size_t)j * 65536);
    }
}

extern "C" void kernel_launch(void* const* d_in, const int* in_sizes, int n_in,
                              void* d_out, int out_size, void* d_ws, size_t ws_size,
                              hipStream_t stream) {
    const float* x     = (const float*)d_in[0];
    const float* alpha = (const float*)d_in[1];
    const float* beta  = (const float*)d_in[2];
    const float* wfc   = (const float*)d_in[3];
    const float* w1    = (const float*)d_in[4];
    const float* w2    = (const float*)d_in[5];
    float* out = (float*)d_out;
    float* ws  = (float*)d_ws;

    float* avg     = ws;
    float* mx      = ws + 32768;
    int*   mask_c  = (int*)(ws + 65536);   // mask_t, cnt contiguous after it
    int*   mask_t  = (int*)(ws + 66560);
    int*   cnt     = (int*)(ws + 67584);
    float* flag    = ws + 67616;
    float* im_map  = ws + 68640;
    float* sub_map = ws + 101408;
    float* part    = ws + 134176;

    k1_reduce <<<8192,  256, 0, stream>>>(x, avg, mx, mask_c);  // zeros masks+cnt
    k2_map    <<<256,   256, 0, stream>>>(avg, mx, alpha, beta, wfc, mask_c, mask_t);
    k4_partial<<<512,   256, 0, stream>>>(x, mask_c, mask_t, cnt, flag, part,
                                          w1, w2, im_map, sub_map);
    k6_out    <<<8192,  256, 0, stream>>>(x, flag, im_map, sub_map, out);
}

// Round 7
// 94.491 us; speedup vs baseline: 1.5884x; 1.5884x over previous
//
#include <hip/hip_runtime.h>
#include <math.h>

// Problem dims (fixed by setup_inputs): n=32, t=8, c=128, h=w=32
#define TC  1024   // t*c channels
#define P_  1024   // h*w pixels
#define KC  64     // int(c*0.5)
#define KT  4      // int(t*0.5)

typedef float vfloat4 __attribute__((ext_vector_type(4)));   // native vec for NT store

// workspace layout (float offsets):
//   avg    [0,      32768)    per (n,t,c) spatial mean
//   mx     [32768,  65536)    per (n,t,c) spatial max
//   mask_c [65536,  66560)    int, batch-union channel-topk mask
//   mask_t [66560,  67584)    int, batch-union time-topk mask
//   flag   [67584,  68608)    float XOR mask (im=1)
//   im_map [68608,  101376)   [n][pix]
//   sub_map[101376, 134144)   [n][pix]
//   part   [134144, 658432)   [cq=4][n=32][stat=4][pix=1024] pooled partials

// ---------- K1: spatial mean/max, one wave per (n,t,c) row -------------------
// 8192 blocks x 256 thr = 4 waves; wave w handles row blockIdx*4+w.
// Lane l reads float4s l, l+64, l+128, l+192 (coalesced, ILP 4), then a pure
// 6-step shfl reduce — no LDS, no __syncthreads. Block 0 also zeros the masks
// (2048 ints; stream-ordered before K2 consumes them).
__global__ __launch_bounds__(256) void k1_reduce(const float* __restrict__ x,
                                                 float* __restrict__ avg,
                                                 float* __restrict__ mx,
                                                 int* __restrict__ masks) {
    if (blockIdx.x == 0) {
        for (int j = threadIdx.x; j < 2048; j += 256) masks[j] = 0;
    }
    int wid = threadIdx.x >> 6, lane = threadIdx.x & 63;
    int r = blockIdx.x * 4 + wid;             // r = n*1024 + t*128 + c
    const float4* xp = (const float4*)(x + (size_t)r * P_) + lane;
    float4 a = xp[0], b = xp[64], c = xp[128], d = xp[192];
    float s = ((a.x + a.y) + (a.z + a.w)) + ((b.x + b.y) + (b.z + b.w))
            + ((c.x + c.y) + (c.z + c.w)) + ((d.x + d.y) + (d.z + d.w));
    float m = fmaxf(fmaxf(fmaxf(fmaxf(a.x, a.y), fmaxf(a.z, a.w)),
                          fmaxf(fmaxf(b.x, b.y), fmaxf(b.z, b.w))),
                    fmaxf(fmaxf(fmaxf(c.x, c.y), fmaxf(c.z, c.w)),
                          fmaxf(fmaxf(d.x, d.y), fmaxf(d.z, d.w))));
    #pragma unroll
    for (int off = 32; off > 0; off >>= 1) {
        s += __shfl_down(s, off);
        m  = fmaxf(m, __shfl_down(m, off));
    }
    if (lane == 0) {
        avg[r] = s * (1.0f / 1024.0f);
        mx[r]  = m;
    }
}

// ---------- K2: map_add + fc + exact top-k rank masks; block = (n, tt) -------
__global__ __launch_bounds__(256) void k2_map(const float* __restrict__ avg,
                                              const float* __restrict__ mx,
                                              const float* __restrict__ alpha,
                                              const float* __restrict__ beta,
                                              const float* __restrict__ wfc,
                                              int* __restrict__ mask_c,
                                              int* __restrict__ mask_t) {
    __shared__ float m[TC], mf[TC], w[64];
    int n = blockIdx.x >> 3, tt = blockIdx.x & 7;
    float a0 = alpha[0], b0 = beta[0];
    if (threadIdx.x < 64) w[threadIdx.x] = wfc[threadIdx.x];
    for (int i = threadIdx.x; i < TC; i += 256) {
        float a = avg[n * TC + i], b = mx[n * TC + i];
        m[i] = 0.5f * (a + b) + a0 * a + b0 * b;
    }
    __syncthreads();
    // fc along time: mf[s*128+c] = sum_t m[t*128+c] * W[s][t]
    for (int i = threadIdx.x; i < TC; i += 256) {
        int s = i >> 7, cc = i & 127;
        float acc = 0.0f;
        #pragma unroll
        for (int t2 = 0; t2 < 8; ++t2) acc += m[t2 * 128 + cc] * w[s * 8 + t2];
        mf[i] = acc;
    }
    __syncthreads();
    // exact lax.top_k emulation for row tt: selected iff
    //   #{j: v_j > v_i} + #{j: v_j == v_i && j < i} < k
    if (threadIdx.x < 128) {
        int cc = threadIdx.x, i = tt * 128 + cc;
        float v = mf[i];
        int rc = 0;
        #pragma unroll 16
        for (int c2 = 0; c2 < 128; ++c2) {
            float u = mf[tt * 128 + c2];
            rc += (u > v) || (u == v && c2 < cc);
        }
        if (rc < KC) mask_c[i] = 1;   // benign race: all writers store 1
        int rt = 0;
        #pragma unroll
        for (int t2 = 0; t2 < 8; ++t2) {
            float u = mf[t2 * 128 + cc];
            rt += (u > v) || (u == v && t2 < tt);
        }
        if (rt < KT) mask_t[i] = 1;
    }
}

// ---------- K4: masked channel stats; block = (n, pix-quarter, chan-quarter) --
// 512 blocks x 256 thr. Thread (cg = tid>>6, l = tid&63) accumulates 64
// channels for float4-pixel pq*64+l; LDS-reduce across the 4 cg subgroups;
// write pooled partials [cq][n][stat][pix].
__global__ __launch_bounds__(256) void k4_partial(const float* __restrict__ x,
                                                  const int* __restrict__ mask_c,
                                                  const int* __restrict__ mask_t,
                                                  float* __restrict__ flag_out,
                                                  float* __restrict__ part) {
    int b = blockIdx.x;
    int cq = b & 3, pq = (b >> 2) & 3, n = b >> 4;
    __shared__ float sf[256];
    __shared__ float4 red[4][4][64];   // [stat][cg][l]
    {
        int i = threadIdx.x;
        int ch = cq * 256 + i;
        float f = ((mask_c[ch] != 0) != (mask_t[ch] != 0)) ? 1.0f : 0.0f;
        sf[i] = f;
        if (n == 0 && pq == 0) flag_out[ch] = f;
    }
    __syncthreads();
    int l = threadIdx.x & 63, cg = threadIdx.x >> 6;
    int f4p = pq * 64 + l;
    int ch0 = cq * 256 + cg * 64;
    const float4* xb = (const float4*)x + ((size_t)(n * TC + ch0)) * 256 + f4p;
    float4 ims  = {0.f, 0.f, 0.f, 0.f};
    float4 subs = {0.f, 0.f, 0.f, 0.f};
    float4 imm  = {-INFINITY, -INFINITY, -INFINITY, -INFINITY};
    float4 subm = {-INFINITY, -INFINITY, -INFINITY, -INFINITY};
    #pragma unroll 8
    for (int k = 0; k < 64; ++k) {
        float4 v = xb[(size_t)k * 256];
        float f = sf[cg * 64 + k];
        float iv;
        iv = v.x * f; ims.x += iv; imm.x = fmaxf(imm.x, iv);
        v.x -= iv;    subs.x += v.x; subm.x = fmaxf(subm.x, v.x);
        iv = v.y * f; ims.y += iv; imm.y = fmaxf(imm.y, iv);
        v.y -= iv;    subs.y += v.y; subm.y = fmaxf(subm.y, v.y);
        iv = v.z * f; ims.z += iv; imm.z = fmaxf(imm.z, iv);
        v.z -= iv;    subs.z += v.z; subm.z = fmaxf(subm.z, v.z);
        iv = v.w * f; ims.w += iv; imm.w = fmaxf(imm.w, iv);
        v.w -= iv;    subs.w += v.w; subm.w = fmaxf(subm.w, v.w);
    }
    red[0][cg][l] = ims;
    red[1][cg][l] = imm;
    red[2][cg][l] = subs;
    red[3][cg][l] = subm;
    __syncthreads();
    if (threadIdx.x < 64) {
        float4 s0 = red[0][0][l], s1 = red[1][0][l], s2 = red[2][0][l], s3 = red[3][0][l];
        #pragma unroll
        for (int g = 1; g < 4; ++g) {
            float4 a = red[0][g][l], bq = red[1][g][l], c = red[2][g][l], d = red[3][g][l];
            s0.x += a.x; s0.y += a.y; s0.z += a.z; s0.w += a.w;
            s1.x = fmaxf(s1.x, bq.x); s1.y = fmaxf(s1.y, bq.y);
            s1.z = fmaxf(s1.z, bq.z); s1.w = fmaxf(s1.w, bq.w);
            s2.x += c.x; s2.y += c.y; s2.z += c.z; s2.w += c.w;
            s3.x = fmaxf(s3.x, d.x); s3.y = fmaxf(s3.y, d.y);
            s3.z = fmaxf(s3.z, d.z); s3.w = fmaxf(s3.w, d.w);
        }
        float4* pp = (float4*)part + ((size_t)(cq * 32 + n) * 4) * 256 + f4p;
        pp[0]   = s0;
        pp[256] = s1;
        pp[512] = s2;
        pp[768] = s3;
    }
}

// ---------- K5: combine 4 chan-quarters -> pooled (LDS) -> 3x3 conv + sigmoid -
__global__ __launch_bounds__(1024) void k5_conv(const float* __restrict__ part,
                                                const float* __restrict__ w1,
                                                const float* __restrict__ w2,
                                                float* __restrict__ im_map,
                                                float* __restrict__ sub_map) {
    __shared__ float sp[4][P_];
    int n = blockIdx.x, p = threadIdx.x;
    float s_im = 0.f, s_sub = 0.f, m_im = -INFINITY, m_sub = -INFINITY;
    #pragma unroll
    for (int q = 0; q < 4; ++q) {
        size_t base = ((size_t)(q * 32 + n) * 4) * P_ + p;
        s_im  += part[base];
        m_im   = fmaxf(m_im, part[base + 1024]);
        s_sub += part[base + 2048];
        m_sub  = fmaxf(m_sub, part[base + 3072]);
    }
    sp[0][p] = s_im  * (2.0f / 1024.0f);   // mean / LAM
    sp[1][p] = m_im;
    sp[2][p] = s_sub * (2.0f / 1024.0f);   // mean / (1-LAM)
    sp[3][p] = m_sub;
    __syncthreads();
    int y = p >> 5, xx = p & 31;
    float acc1 = 0.0f, acc2 = 0.0f;
    #pragma unroll
    for (int i = 0; i < 2; ++i)
        #pragma unroll
        for (int dy = 0; dy < 3; ++dy) {
            int yy = y + dy - 1;
            if (yy < 0 || yy >= 32) continue;
            #pragma unroll
            for (int dx = 0; dx < 3; ++dx) {
                int xc = xx + dx - 1;
                if (xc < 0 || xc >= 32) continue;
                acc1 += sp[i][yy * 32 + xc]     * w1[i * 9 + dy * 3 + dx];
                acc2 += sp[2 + i][yy * 32 + xc] * w2[i * 9 + dy * 3 + dx];
            }
        }
    im_map[n * P_ + p]  = 1.0f / (1.0f + expf(-acc1));
    sub_map[n * P_ + p] = 1.0f / (1.0f + expf(-acc2));
}

// ---------- K6: out = x * (flag ? im_map : sub_map); 4 float4/thr, NT stores --
// g = global thread id; n = g>>16; rem = g&65535 -> ch = rem>>8, pixf4 = rem&255.
// j-step adds 256 channels (65536 float4) within the same n; full coverage of
// [0, 262144) float4 per n, same map pixel for all 4 steps.
__global__ __launch_bounds__(256) void k6_out(const float* __restrict__ x,
                                              const float* __restrict__ flag,
                                              const float* __restrict__ im_map,
                                              const float* __restrict__ sub_map,
                                              float* __restrict__ out) {
    int g   = blockIdx.x * 256 + threadIdx.x;   // 0 .. 2097151
    int n   = g >> 16;
    int rem = g & 65535;
    int ch    = rem >> 8;                       // 0..255 (channel row base)
    int pixf4 = rem & 255;
    size_t base = ((size_t)n << 18) + rem;      // float4 index
    const float4* xp = (const float4*)x + base;
    const float4* imb  = (const float4*)im_map  + n * 256 + pixf4;
    const float4* subb = (const float4*)sub_map + n * 256 + pixf4;
    float4 im_v  = *imb;
    float4 sub_v = *subb;
    #pragma unroll
    for (int j = 0; j < 4; ++j) {
        float4 xv = xp[j * 65536];              // +256 channels, same pixel
        bool im = flag[ch + j * 256] != 0.0f;
        float4 mv = im ? im_v : sub_v;
        vfloat4 o;
        o.x = xv.x * mv.x; o.y = xv.y * mv.y; o.z = xv.z * mv.z; o.w = xv.w * mv.w;
        __builtin_nontemporal_store(o, (vfloat4*)out + base + (size_t)j * 65536);
    }
}

extern "C" void kernel_launch(void* const* d_in, const int* in_sizes, int n_in,
                              void* d_out, int out_size, void* d_ws, size_t ws_size,
                              hipStream_t stream) {
    const float* x     = (const float*)d_in[0];
    const float* alpha = (const float*)d_in[1];
    const float* beta  = (const float*)d_in[2];
    const float* wfc   = (const float*)d_in[3];
    const float* w1    = (const float*)d_in[4];
    const float* w2    = (const float*)d_in[5];
    float* out = (float*)d_out;
    float* ws  = (float*)d_ws;

    float* avg     = ws;
    float* mx      = ws + 32768;
    int*   mask_c  = (int*)(ws + 65536);   // mask_t contiguous after it
    int*   mask_t  = (int*)(ws + 66560);
    float* flag    = ws + 67584;
    float* im_map  = ws + 68608;
    float* sub_map = ws + 101376;
    float* part    = ws + 134144;

    k1_reduce <<<8192,  256, 0, stream>>>(x, avg, mx, mask_c);  // zeros masks
    k2_map    <<<256,   256, 0, stream>>>(avg, mx, alpha, beta, wfc, mask_c, mask_t);
    k4_partial<<<512,   256, 0, stream>>>(x, mask_c, mask_t, flag, part);
    k5_conv   <<<32,   1024, 0, stream>>>(part, w1, w2, im_map, sub_map);
    k6_out    <<<8192,  256, 0, stream>>>(x, flag, im_map, sub_map, out);
}